// Round 11
// baseline (240.382 us; speedup 1.0000x reference)
//
#include <hip/hip_runtime.h>
#include <stdint.h>

#define T_STEPS 8192
#define LSEQ    8192
#define H       256
#define D       64
#define PSCALE  0.125f   // 1/sqrt(64)
#define CONV_EPS 4e-4f   // convergence tolerance (validated: nw ~ 7)
#define NCH     16       // score chunks per row
#define CHK     512      // keys per chunk (NCH*CHK == LSEQ)
#define NBLK    240      // mega grid: <= 256 CUs -> 1 block/CU, all co-resident

typedef _Float16 half2_t __attribute__((ext_vector_type(2)));

#if __has_builtin(__builtin_amdgcn_fdot2)
#define FDOT2(a, b, c) __builtin_amdgcn_fdot2((a), (b), (c), false)
#else
#define FDOT2(a, b, c) fmaf((float)(a).x, (float)(b).x, fmaf((float)(a).y, (float)(b).y, (c)))
#endif

static __device__ __forceinline__ unsigned pack_f16(float a, float b) {
    half2_t h; h.x = (_Float16)a; h.y = (_Float16)b;
    return __builtin_bit_cast(unsigned, h);
}

// Device-scope grid barrier. Safe because all NBLK blocks are co-resident
// (NBLK=240 <= 256 CUs; 512-thr, <=256-VGPR blocks = 1 block/CU, so the CP
// cannot strand a block). Generation counter + s_sleep backoff. The
// __threadfence() is the cross-XCD release for all prior plain stores; all
// cross-phase data is first-touched by consumers only after the barrier.
static __device__ __forceinline__ void gridbar(int* cnt, int* gen) {
    __syncthreads();
    if (threadIdx.x == 0) {
        __threadfence();
        int g = __hip_atomic_load(gen, __ATOMIC_RELAXED, __HIP_MEMORY_SCOPE_AGENT);
        int a = __hip_atomic_fetch_add(cnt, 1, __ATOMIC_ACQ_REL, __HIP_MEMORY_SCOPE_AGENT);
        if (a == NBLK - 1) {
            __hip_atomic_store(cnt, 0, __ATOMIC_RELAXED, __HIP_MEMORY_SCOPE_AGENT);
            __hip_atomic_fetch_add(gen, 1, __ATOMIC_ACQ_REL, __HIP_MEMORY_SCOPE_AGENT);
        } else {
            while (__hip_atomic_load(gen, __ATOMIC_ACQUIRE, __HIP_MEMORY_SCOPE_AGENT) == g)
                __builtin_amdgcn_s_sleep(15);
        }
        __threadfence();
    }
    __syncthreads();
}

// ---------------------------------------------------------------------------
// K0: prep — chip-wide weight staging (f16 SoA for the rnn, WT transposes for
// coalesced projections) + zero-init of the grid-barrier words.
// ---------------------------------------------------------------------------
__global__ __launch_bounds__(256) void prep_k(
    const float* __restrict__ W_ih, const float* __restrict__ Wk,
    const float* __restrict__ Wq, uint4* __restrict__ W16v,
    float* __restrict__ WTk, float* __restrict__ WTq,
    int* __restrict__ bar_cnt, int* __restrict__ bar_gen)
{
    if (blockIdx.x == 0 && threadIdx.x == 0) { *bar_cnt = 0; *bar_gen = 0; }
    int flat = blockIdx.x * 256 + threadIdx.x;
    if (flat < 24576) {                 // W16v: 48*512 uint4 (SoA, coalesced)
        int p = flat >> 9, slot = flat & 511;
        int g = p >> 4, s = p & 15;
        int j = slot >> 1, kc = slot & 1;
        const int goff = (g == 0) ? 0 : (g == 1 ? 512 : 768);
        const float* src = W_ih + (size_t)(goff + j) * H + kc * 128 + s * 8;
        uint4 u;
        u.x = pack_f16(src[0], src[1]);
        u.y = pack_f16(src[2], src[3]);
        u.z = pack_f16(src[4], src[5]);
        u.w = pack_f16(src[6], src[7]);
        W16v[flat] = u;
    } else if (flat < 24576 + 4096) {   // WT transposes: 4096 float4 each
        int f = flat - 24576;
        int d = f & 63, k0 = f >> 6;
        ((float4*)WTk)[f] = *(const float4*)(Wk + d * H + k0 * 4);
        ((float4*)WTq)[f] = *(const float4*)(Wq + d * H + k0 * 4);
    }
}

// ---------------------------------------------------------------------------
// K1: the persistent mega-kernel (2 dispatches total for the whole problem).
// P1: block 0 = LSTM recurrence; blocks 1..239 = Kp projection.   [gridbar]
// P2: attnA chunk-softmax items (inline Q proj) + hs[nw..T) fill. [gridbar]
// P3: LSE combine + normalize + duplicate-row replicate (write-bound tail).
// ---------------------------------------------------------------------------
__global__ __launch_bounds__(512, 2) void mega_k(
    const float* __restrict__ enc, const uint4* __restrict__ W16v,
    const float* __restrict__ b_ih, const float* __restrict__ b_hh,
    const float* __restrict__ WTk, const float* __restrict__ bk,
    const float* __restrict__ WTq, const float* __restrict__ bq,
    float* __restrict__ Kp, float* __restrict__ hs_out,
    float* __restrict__ hstar, int* __restrict__ nw_p,
    int* __restrict__ bar_cnt, int* __restrict__ bar_gen, int cap,
    float* __restrict__ cmax, float* __restrict__ csum,
    float* __restrict__ scores, float* __restrict__ out)
{
    const int tid = threadIdx.x;
    const int bid = blockIdx.x;

    __shared__ half2_t hp[H / 2];
    __shared__ float qrow[D];
    __shared__ float red[8];

    // ================= P1: rnn (block 0) || Kp (blocks 1..239) =============
    if (bid == 0) {
        const int j  = tid >> 1;
        const int kc = tid & 1;

        uint4 wv[48];                    // 48 coalesced uint4 = 3x128 f16 wts
#pragma unroll
        for (int p = 0; p < 48; ++p) wv[p] = W16v[p * 512 + tid];

        const float bi = b_ih[j] + b_hh[j];
        const float bg = b_ih[512 + j] + b_hh[512 + j];
        const float bo = b_ih[768 + j] + b_hh[768 + j];

        float hcur = enc[(size_t)(LSEQ - 1) * H + j];   // h0 = enc[-1]
        {
            float hnext = __shfl_xor(hcur, 2);
            if ((tid & 3) == 0) { half2_t p; p.x = (_Float16)hcur; p.y = (_Float16)hnext; hp[tid >> 2] = p; }
        }
        __syncthreads();

        int nw = T_STEPS, streak = 0;
        for (int t = 1; t <= T_STEPS; ++t) {
            float ai = 0.f, ag = 0.f, ao = 0.f;
            const uint4* hp4 = (const uint4*)hp;
#pragma unroll
            for (int q = 0; q < 16; ++q) {
                uint4 u = hp4[kc * 16 + q];
                half2_t h0 = __builtin_bit_cast(half2_t, u.x);
                half2_t h1 = __builtin_bit_cast(half2_t, u.y);
                half2_t h2 = __builtin_bit_cast(half2_t, u.z);
                half2_t h3 = __builtin_bit_cast(half2_t, u.w);
                uint4 wiu = wv[q], wgu = wv[16 + q], wou = wv[32 + q];
                ai = FDOT2(__builtin_bit_cast(half2_t, wiu.x), h0, ai);
                ag = FDOT2(__builtin_bit_cast(half2_t, wgu.x), h0, ag);
                ao = FDOT2(__builtin_bit_cast(half2_t, wou.x), h0, ao);
                ai = FDOT2(__builtin_bit_cast(half2_t, wiu.y), h1, ai);
                ag = FDOT2(__builtin_bit_cast(half2_t, wgu.y), h1, ag);
                ao = FDOT2(__builtin_bit_cast(half2_t, wou.y), h1, ao);
                ai = FDOT2(__builtin_bit_cast(half2_t, wiu.z), h2, ai);
                ag = FDOT2(__builtin_bit_cast(half2_t, wgu.z), h2, ag);
                ao = FDOT2(__builtin_bit_cast(half2_t, wou.z), h2, ao);
                ai = FDOT2(__builtin_bit_cast(half2_t, wiu.w), h3, ai);
                ag = FDOT2(__builtin_bit_cast(half2_t, wgu.w), h3, ag);
                ao = FDOT2(__builtin_bit_cast(half2_t, wou.w), h3, ao);
            }
            ai += __shfl_xor(ai, 1); ag += __shfl_xor(ag, 1); ao += __shfl_xor(ao, 1);
            ai += bi; ag += bg; ao += bo;

            float si = 1.0f / (1.0f + __expf(-ai));
            float eg = __expf(-2.0f * ag); float tg = (1.0f - eg) / (1.0f + eg);
            float so = 1.0f / (1.0f + __expf(-ao));
            float c  = si * tg;
            float ec = __expf(-2.0f * c);  float tc = (1.0f - ec) / (1.0f + ec);
            float hn = so * tc;

            int moving = (kc == 0 && fabsf(hn - hcur) >= CONV_EPS) ? 1 : 0;
            int nmov = __syncthreads_count(moving);

            hcur = hn;
            float hnext = __shfl_xor(hn, 2);
            if ((tid & 3) == 0) { half2_t p; p.x = (_Float16)hn; p.y = (_Float16)hnext; hp[tid >> 2] = p; }
            if (kc == 0) hs_out[(size_t)(t - 1) * H + j] = hn;
            __syncthreads();

            streak = (nmov == 0) ? streak + 1 : 0;
            if (streak >= 2) { nw = t; break; }
        }
        if (kc == 0) hstar[j] = hcur;
        if (tid == 0)
            __hip_atomic_store(nw_p, nw, __ATOMIC_RELEASE, __HIP_MEMORY_SCOPE_AGENT);
    } else {
        // ---- Kp: 4 rows per wave, coalesced WTk reads ----
        const int lane = tid & 63;
        const float bkl = bk[lane];
        const float4* wk4 = (const float4*)WTk;
        for (int g = (bid - 1) * 8 + (tid >> 6); g < LSEQ / 4; g += (NBLK - 1) * 8) {
            const int r0 = g * 4;
            const float4* e0 = (const float4*)(enc + (size_t)(r0 + 0) * H);
            const float4* e1 = (const float4*)(enc + (size_t)(r0 + 1) * H);
            const float4* e2 = (const float4*)(enc + (size_t)(r0 + 2) * H);
            const float4* e3 = (const float4*)(enc + (size_t)(r0 + 3) * H);
            float s0 = 0.f, s1 = 0.f, s2 = 0.f, s3 = 0.f;
#pragma unroll 8
            for (int k0 = 0; k0 < 64; ++k0) {
                float4 w = wk4[k0 * 64 + lane];
                float4 a0 = e0[k0], a1 = e1[k0], a2 = e2[k0], a3 = e3[k0];
                s0 = fmaf(a0.x, w.x, fmaf(a0.y, w.y, fmaf(a0.z, w.z, fmaf(a0.w, w.w, s0))));
                s1 = fmaf(a1.x, w.x, fmaf(a1.y, w.y, fmaf(a1.z, w.z, fmaf(a1.w, w.w, s1))));
                s2 = fmaf(a2.x, w.x, fmaf(a2.y, w.y, fmaf(a2.z, w.z, fmaf(a2.w, w.w, s2))));
                s3 = fmaf(a3.x, w.x, fmaf(a3.y, w.y, fmaf(a3.z, w.z, fmaf(a3.w, w.w, s3))));
            }
            Kp[(size_t)(r0 + 0) * D + lane] = bkl + s0;
            Kp[(size_t)(r0 + 1) * D + lane] = bkl + s1;
            Kp[(size_t)(r0 + 2) * D + lane] = bkl + s2;
            Kp[(size_t)(r0 + 3) * D + lane] = bkl + s3;
        }
    }

    gridbar(bar_cnt, bar_gen);

    // ================= P2: attnA items + hs fill ============================
    const int nw = __hip_atomic_load(nw_p, __ATOMIC_ACQUIRE, __HIP_MEMORY_SCOPE_AGENT);
    const int na = min(nw, cap);
    const float4* wq4 = (const float4*)WTq;

    for (int it = bid; it < na * NCH; it += NBLK) {
        const int r = it >> 4, c = it & (NCH - 1);
        if (tid < 64) {                  // inline Q projection
            const float4* e4 = (const float4*)(hs_out + (size_t)r * H);
            float s = 0.f;
#pragma unroll 8
            for (int k0 = 0; k0 < 64; ++k0) {
                float4 a = e4[k0];
                float4 w = wq4[k0 * 64 + tid];
                s = fmaf(a.x, w.x, fmaf(a.y, w.y, fmaf(a.z, w.z, fmaf(a.w, w.w, s))));
            }
            qrow[tid] = bq[tid] + s;
        }
        __syncthreads();
        float4 qr[16];
#pragma unroll
        for (int k = 0; k < 16; ++k) qr[k] = ((const float4*)qrow)[k];

        const int k0 = c * CHK + tid;    // 512 threads == CHK: 1 key/thread
        const float4* k4 = (const float4*)(Kp + (size_t)k0 * D);
        float s = 0.f;
#pragma unroll
        for (int k = 0; k < 16; ++k) {
            float4 kv = k4[k];
            s = fmaf(kv.x, qr[k].x, fmaf(kv.y, qr[k].y, fmaf(kv.z, qr[k].z, fmaf(kv.w, qr[k].w, s))));
        }
        s *= PSCALE;
        scores[(size_t)r * LSEQ + k0] = s;

        float m = s;
#pragma unroll
        for (int off = 32; off; off >>= 1) m = fmaxf(m, __shfl_xor(m, off));
        if ((tid & 63) == 0) red[tid >> 6] = m;
        __syncthreads();
        m = red[0];
#pragma unroll
        for (int w = 1; w < 8; ++w) m = fmaxf(m, red[w]);
        __syncthreads();                 // red reuse guard

        float e = __expf(s - m);
#pragma unroll
        for (int off = 32; off; off >>= 1) e += __shfl_xor(e, off);
        if ((tid & 63) == 0) red[tid >> 6] = e;
        __syncthreads();
        if (tid == 0) {
            float v = red[0];
#pragma unroll
            for (int w = 1; w < 8; ++w) v += red[w];
            cmax[it] = m; csum[it] = v;
        }
        __syncthreads();                 // red/qrow guard for next item
    }

    // hs[nw..T) = h*  (8 rows per block iteration, one row per wave)
    {
        float4 hv = ((const float4*)hstar)[tid & 63];
        for (int r = nw + bid * 8 + (tid >> 6); r < T_STEPS; r += NBLK * 8)
            ((float4*)(hs_out + (size_t)r * H))[tid & 63] = hv;
    }

    gridbar(bar_cnt, bar_gen);

    // ================= P3: normalize + replicate (write-bound) ==============
    for (int r = bid; r < T_STEPS; r += NBLK) {
        const int rs = min(r, nw - 1);
        if (rs >= na) continue;          // nw > cap -> host launched fb kernel
        float m = -3.4e38f;
#pragma unroll
        for (int c = 0; c < NCH; ++c) m = fmaxf(m, cmax[rs * NCH + c]);
        float v = 0.f;
#pragma unroll
        for (int c = 0; c < NCH; ++c) v += csum[rs * NCH + c] * __expf(cmax[rs * NCH + c] - m);
        const float inv = 1.0f / v;

        const float4* s4 = (const float4*)(scores + (size_t)rs * LSEQ);
        float4* o4 = (float4*)(out + (size_t)r * LSEQ);
        for (int i = tid; i < LSEQ / 4; i += 512) {
            float4 sv = s4[i];
            float4 ov;
            ov.x = __expf(sv.x - m) * inv;
            ov.y = __expf(sv.y - m) * inv;
            ov.z = __expf(sv.z - m) * inv;
            ov.w = __expf(sv.w - m) * inv;
            o4[i] = ov;
        }
    }
}

// ---------------------------------------------------------------------------
// K2: fallback for source rows >= cap (only when ws can't hold all score
// rows; with the provided ws it never launches). Inline-Q full softmax.
// ---------------------------------------------------------------------------
__global__ __launch_bounds__(256) void attn_fb_k(
    const float* __restrict__ hs, const float* __restrict__ WTq,
    const float* __restrict__ bq, const float* __restrict__ Kp,
    const int* __restrict__ nw_p, int cap, float* __restrict__ out)
{
    const int r = blockIdx.x;
    const int nw = nw_p[0];
    const int rs = min(r, nw - 1);
    if (rs < cap) return;
    const int tid = threadIdx.x;

    __shared__ float srow[LSEQ];
    __shared__ float qrow[D];
    __shared__ float red[4];
    const float4* wq4 = (const float4*)WTq;

    if (tid < 64) {
        const float4* e4 = (const float4*)(hs + (size_t)rs * H);
        float s = 0.f;
#pragma unroll 8
        for (int k0 = 0; k0 < 64; ++k0) {
            float4 a = e4[k0];
            float4 w = wq4[k0 * 64 + tid];
            s = fmaf(a.x, w.x, fmaf(a.y, w.y, fmaf(a.z, w.z, fmaf(a.w, w.w, s))));
        }
        qrow[tid] = bq[tid] + s;
    }
    __syncthreads();
    float4 qr[16];
#pragma unroll
    for (int k = 0; k < 16; ++k) qr[k] = ((const float4*)qrow)[k];

    for (int l = tid; l < LSEQ; l += 256) {
        const float4* k4 = (const float4*)(Kp + (size_t)l * D);
        float s = 0.f;
#pragma unroll
        for (int k = 0; k < 16; ++k) {
            float4 kv = k4[k];
            s = fmaf(kv.x, qr[k].x, fmaf(kv.y, qr[k].y, fmaf(kv.z, qr[k].z, fmaf(kv.w, qr[k].w, s))));
        }
        srow[l] = s * PSCALE;
    }
    __syncthreads();

    float m = -3.4e38f;
    for (int l = tid; l < LSEQ; l += 256) m = fmaxf(m, srow[l]);
#pragma unroll
    for (int off = 32; off; off >>= 1) m = fmaxf(m, __shfl_xor(m, off));
    if ((tid & 63) == 0) red[tid >> 6] = m;
    __syncthreads();
    m = fmaxf(fmaxf(red[0], red[1]), fmaxf(red[2], red[3]));
    __syncthreads();

    float s = 0.f;
    for (int l = tid; l < LSEQ; l += 256) { float e = __expf(srow[l] - m); srow[l] = e; s += e; }
#pragma unroll
    for (int off = 32; off; off >>= 1) s += __shfl_xor(s, off);
    if ((tid & 63) == 0) red[tid >> 6] = s;
    __syncthreads();
    s = red[0] + red[1] + red[2] + red[3];
    float inv = 1.0f / s;

    float4* o4 = (float4*)(out + (size_t)r * LSEQ);
    const float4* s4 = (const float4*)srow;
    for (int i = tid; i < LSEQ / 4; i += 256) {
        float4 v = s4[i];
        v.x *= inv; v.y *= inv; v.z *= inv; v.w *= inv;
        o4[i] = v;
    }
}

extern "C" void kernel_launch(void* const* d_in, const int* in_sizes, int n_in,
                              void* d_out, int out_size, void* d_ws, size_t ws_size,
                              hipStream_t stream)
{
    const float* enc  = (const float*)d_in[1];
    const float* W_ih = (const float*)d_in[2];
    // d_in[3] = W_hh multiplies the always-zero LSTM hidden state -> unused.
    const float* b_ih = (const float*)d_in[4];
    const float* b_hh = (const float*)d_in[5];
    const float* Wq   = (const float*)d_in[6];
    const float* bq   = (const float*)d_in[7];
    const float* Wk   = (const float*)d_in[8];
    const float* bk   = (const float*)d_in[9];

    float* out = (float*)d_out;                       // pointers: 8192*8192
    float* hs  = out + (size_t)T_STEPS * LSEQ;        // hs: 8192*256 (2nd output)

    // ws layout (floats): nw(32) | bar_cnt@32 | bar_gen@48 | hstar@64(256) |
    //   Kp(512K) | WTk(16K) | WTq(16K) | W16v(98304) | cmax(CAP*16) |
    //   csum(CAP*16) | scores(CAP*8192)
    float* wsf     = (float*)d_ws;
    int*   nw_p    = (int*)d_ws;
    int*   bar_cnt = (int*)(wsf + 32);
    int*   bar_gen = (int*)(wsf + 48);
    float* hstar   = wsf + 64;
    float* Kp      = wsf + 64 + 256;
    float* WTk     = Kp + (size_t)LSEQ * D;
    float* WTq     = WTk + 64 * H;
    uint4* W16v    = (uint4*)(WTq + 64 * H);
    size_t off_dyn = 64 + 256 + (size_t)LSEQ * D + 2 * (size_t)64 * H + 24576 * 4;

    size_t wsf_count = ws_size / 4;
    long cap_l = 0;
    if (wsf_count > off_dyn)
        cap_l = (long)((wsf_count - off_dyn) / (LSEQ + 2 * NCH));
    if (cap_l > T_STEPS) cap_l = T_STEPS;
    const int CAP = (int)cap_l;

    float* cmax   = wsf + off_dyn;
    float* csum   = cmax + (size_t)CAP * NCH;
    float* scores = csum + (size_t)CAP * NCH;

    prep_k<<<112, 256, 0, stream>>>(W_ih, Wk, Wq, W16v, WTk, WTq, bar_cnt, bar_gen);
    mega_k<<<NBLK, 512, 0, stream>>>(enc, W16v, b_ih, b_hh, WTk, bk, WTq, bq,
                                     Kp, hs, hstar, nw_p, bar_cnt, bar_gen, CAP,
                                     cmax, csum, scores, out);
    if (CAP < T_STEPS)
        attn_fb_k<<<T_STEPS, 256, 0, stream>>>(hs, WTq, bq, Kp, nw_p, CAP, out);
}

// Round 12
// 187.385 us; speedup vs baseline: 1.2828x; 1.2828x over previous
//
#include <hip/hip_runtime.h>
#include <stdint.h>

#define T_STEPS 8192
#define LSEQ    8192
#define H       256
#define D       64
#define PSCALE  0.125f   // 1/sqrt(64)
#define CONV_EPS 4e-4f   // convergence tolerance (validated: nw ~ 7)
#define NCH     16       // score chunks per row
#define CHK     512      // keys per chunk (NCH*CHK == LSEQ)
#define NBLK    240      // mid grid: <= 256 CUs -> all co-resident (proven r11)

typedef _Float16 half2_t __attribute__((ext_vector_type(2)));

#if __has_builtin(__builtin_amdgcn_fdot2)
#define FDOT2(a, b, c) __builtin_amdgcn_fdot2((a), (b), (c), false)
#else
#define FDOT2(a, b, c) fmaf((float)(a).x, (float)(b).x, fmaf((float)(a).y, (float)(b).y, (c)))
#endif

static __device__ __forceinline__ unsigned pack_f16(float a, float b) {
    half2_t h; h.x = (_Float16)a; h.y = (_Float16)b;
    return __builtin_bit_cast(unsigned, h);
}

// Device-scope grid barrier (correctness proven in r11's mega_k).
// All NBLK=240 blocks co-resident: 512-thr, ~112-VGPR blocks -> >=1 block/CU.
static __device__ __forceinline__ void gridbar(int* cnt, int* gen) {
    __syncthreads();
    if (threadIdx.x == 0) {
        __threadfence();
        int g = __hip_atomic_load(gen, __ATOMIC_RELAXED, __HIP_MEMORY_SCOPE_AGENT);
        int a = __hip_atomic_fetch_add(cnt, 1, __ATOMIC_ACQ_REL, __HIP_MEMORY_SCOPE_AGENT);
        if (a == NBLK - 1) {
            __hip_atomic_store(cnt, 0, __ATOMIC_RELAXED, __HIP_MEMORY_SCOPE_AGENT);
            __hip_atomic_fetch_add(gen, 1, __ATOMIC_ACQ_REL, __HIP_MEMORY_SCOPE_AGENT);
        } else {
            while (__hip_atomic_load(gen, __ATOMIC_ACQUIRE, __HIP_MEMORY_SCOPE_AGENT) == g)
                __builtin_amdgcn_s_sleep(15);
        }
        __threadfence();
    }
    __syncthreads();
}

// ---------------------------------------------------------------------------
// K0: prep — chip-wide weight staging (f16 SoA for the rnn; WT transposes for
// coalesced projections) + barrier-word init. 112 blocks = 28672 threads.
// ---------------------------------------------------------------------------
__global__ __launch_bounds__(256) void prep_k(
    const float* __restrict__ W_ih, const float* __restrict__ Wk,
    const float* __restrict__ Wq, uint4* __restrict__ W16v,
    float* __restrict__ WTk, float* __restrict__ WTq,
    int* __restrict__ bar_cnt, int* __restrict__ bar_gen)
{
    if (blockIdx.x == 0 && threadIdx.x == 0) { *bar_cnt = 0; *bar_gen = 0; }
    int flat = blockIdx.x * 256 + threadIdx.x;
    if (flat < 24576) {                 // W16v: 48*512 uint4 (SoA, coalesced)
        int p = flat >> 9, slot = flat & 511;
        int g = p >> 4, s = p & 15;
        int j = slot >> 1, kc = slot & 1;
        const int goff = (g == 0) ? 0 : (g == 1 ? 512 : 768);
        const float* src = W_ih + (size_t)(goff + j) * H + kc * 128 + s * 8;
        uint4 u;
        u.x = pack_f16(src[0], src[1]);
        u.y = pack_f16(src[2], src[3]);
        u.z = pack_f16(src[4], src[5]);
        u.w = pack_f16(src[6], src[7]);
        W16v[flat] = u;
    } else if (flat < 24576 + 4096) {   // WT transposes: 4096 float4 each
        int f = flat - 24576;
        int d = f & 63, k0 = f >> 6;
        ((float4*)WTk)[f] = *(const float4*)(Wk + d * H + k0 * 4);
        ((float4*)WTq)[f] = *(const float4*)(Wq + d * H + k0 * 4);
    }
}

// ---------------------------------------------------------------------------
// K1: mid — the two NARROW phases fused (both verified in r11's mega_k):
// P1: block 0 = LSTM recurrence; blocks 1..239 = Kp projection.  [gridbar]
// P2: attnA chunk-softmax items (inline Q proj) + hs[nw..T) fill.
// The write-bound tail is NOT here: r11 proved a <=1-block/CU persistent
// kernel caps HBM writes at ~1.1 TB/s (8 waves/CU, too little MLP).
// ---------------------------------------------------------------------------
__global__ __launch_bounds__(512, 2) void mid_k(
    const float* __restrict__ enc, const uint4* __restrict__ W16v,
    const float* __restrict__ b_ih, const float* __restrict__ b_hh,
    const float* __restrict__ WTk, const float* __restrict__ bk,
    const float* __restrict__ WTq, const float* __restrict__ bq,
    float* __restrict__ Kp, float* __restrict__ hs_out,
    float* __restrict__ hstar, int* __restrict__ nw_p,
    int* __restrict__ bar_cnt, int* __restrict__ bar_gen, int cap,
    float* __restrict__ cmax, float* __restrict__ csum,
    float* __restrict__ scores)
{
    const int tid = threadIdx.x;
    const int bid = blockIdx.x;

    __shared__ half2_t hp[H / 2];
    __shared__ float qrow[D];
    __shared__ float red[8];

    // ================= P1: rnn (block 0) || Kp (blocks 1..239) =============
    if (bid == 0) {
        const int j  = tid >> 1;
        const int kc = tid & 1;

        uint4 wv[48];                    // 48 coalesced uint4 = 3x128 f16 wts
#pragma unroll
        for (int p = 0; p < 48; ++p) wv[p] = W16v[p * 512 + tid];

        const float bi = b_ih[j] + b_hh[j];
        const float bg = b_ih[512 + j] + b_hh[512 + j];
        const float bo = b_ih[768 + j] + b_hh[768 + j];

        float hcur = enc[(size_t)(LSEQ - 1) * H + j];   // h0 = enc[-1]
        {
            float hnext = __shfl_xor(hcur, 2);
            if ((tid & 3) == 0) { half2_t p; p.x = (_Float16)hcur; p.y = (_Float16)hnext; hp[tid >> 2] = p; }
        }
        __syncthreads();

        int nw = T_STEPS, streak = 0;
        for (int t = 1; t <= T_STEPS; ++t) {
            float ai = 0.f, ag = 0.f, ao = 0.f;
            const uint4* hp4 = (const uint4*)hp;
#pragma unroll
            for (int q = 0; q < 16; ++q) {
                uint4 u = hp4[kc * 16 + q];
                half2_t h0 = __builtin_bit_cast(half2_t, u.x);
                half2_t h1 = __builtin_bit_cast(half2_t, u.y);
                half2_t h2 = __builtin_bit_cast(half2_t, u.z);
                half2_t h3 = __builtin_bit_cast(half2_t, u.w);
                uint4 wiu = wv[q], wgu = wv[16 + q], wou = wv[32 + q];
                ai = FDOT2(__builtin_bit_cast(half2_t, wiu.x), h0, ai);
                ag = FDOT2(__builtin_bit_cast(half2_t, wgu.x), h0, ag);
                ao = FDOT2(__builtin_bit_cast(half2_t, wou.x), h0, ao);
                ai = FDOT2(__builtin_bit_cast(half2_t, wiu.y), h1, ai);
                ag = FDOT2(__builtin_bit_cast(half2_t, wgu.y), h1, ag);
                ao = FDOT2(__builtin_bit_cast(half2_t, wou.y), h1, ao);
                ai = FDOT2(__builtin_bit_cast(half2_t, wiu.z), h2, ai);
                ag = FDOT2(__builtin_bit_cast(half2_t, wgu.z), h2, ag);
                ao = FDOT2(__builtin_bit_cast(half2_t, wou.z), h2, ao);
                ai = FDOT2(__builtin_bit_cast(half2_t, wiu.w), h3, ai);
                ag = FDOT2(__builtin_bit_cast(half2_t, wgu.w), h3, ag);
                ao = FDOT2(__builtin_bit_cast(half2_t, wou.w), h3, ao);
            }
            ai += __shfl_xor(ai, 1); ag += __shfl_xor(ag, 1); ao += __shfl_xor(ao, 1);
            ai += bi; ag += bg; ao += bo;

            float si = 1.0f / (1.0f + __expf(-ai));
            float eg = __expf(-2.0f * ag); float tg = (1.0f - eg) / (1.0f + eg);
            float so = 1.0f / (1.0f + __expf(-ao));
            float c  = si * tg;
            float ec = __expf(-2.0f * c);  float tc = (1.0f - ec) / (1.0f + ec);
            float hn = so * tc;

            int moving = (kc == 0 && fabsf(hn - hcur) >= CONV_EPS) ? 1 : 0;
            int nmov = __syncthreads_count(moving);

            hcur = hn;
            float hnext = __shfl_xor(hn, 2);
            if ((tid & 3) == 0) { half2_t p; p.x = (_Float16)hn; p.y = (_Float16)hnext; hp[tid >> 2] = p; }
            if (kc == 0) hs_out[(size_t)(t - 1) * H + j] = hn;
            __syncthreads();

            streak = (nmov == 0) ? streak + 1 : 0;
            if (streak >= 2) { nw = t; break; }
        }
        if (kc == 0) hstar[j] = hcur;
        if (tid == 0)
            __hip_atomic_store(nw_p, nw, __ATOMIC_RELEASE, __HIP_MEMORY_SCOPE_AGENT);
    } else {
        // ---- Kp: 4 rows per wave, coalesced WTk reads ----
        const int lane = tid & 63;
        const float bkl = bk[lane];
        const float4* wk4 = (const float4*)WTk;
        for (int g = (bid - 1) * 8 + (tid >> 6); g < LSEQ / 4; g += (NBLK - 1) * 8) {
            const int r0 = g * 4;
            const float4* e0 = (const float4*)(enc + (size_t)(r0 + 0) * H);
            const float4* e1 = (const float4*)(enc + (size_t)(r0 + 1) * H);
            const float4* e2 = (const float4*)(enc + (size_t)(r0 + 2) * H);
            const float4* e3 = (const float4*)(enc + (size_t)(r0 + 3) * H);
            float s0 = 0.f, s1 = 0.f, s2 = 0.f, s3 = 0.f;
#pragma unroll 8
            for (int k0 = 0; k0 < 64; ++k0) {
                float4 w = wk4[k0 * 64 + lane];
                float4 a0 = e0[k0], a1 = e1[k0], a2 = e2[k0], a3 = e3[k0];
                s0 = fmaf(a0.x, w.x, fmaf(a0.y, w.y, fmaf(a0.z, w.z, fmaf(a0.w, w.w, s0))));
                s1 = fmaf(a1.x, w.x, fmaf(a1.y, w.y, fmaf(a1.z, w.z, fmaf(a1.w, w.w, s1))));
                s2 = fmaf(a2.x, w.x, fmaf(a2.y, w.y, fmaf(a2.z, w.z, fmaf(a2.w, w.w, s2))));
                s3 = fmaf(a3.x, w.x, fmaf(a3.y, w.y, fmaf(a3.z, w.z, fmaf(a3.w, w.w, s3))));
            }
            Kp[(size_t)(r0 + 0) * D + lane] = bkl + s0;
            Kp[(size_t)(r0 + 1) * D + lane] = bkl + s1;
            Kp[(size_t)(r0 + 2) * D + lane] = bkl + s2;
            Kp[(size_t)(r0 + 3) * D + lane] = bkl + s3;
        }
    }

    gridbar(bar_cnt, bar_gen);

    // ================= P2: attnA items + hs fill ============================
    const int nw = __hip_atomic_load(nw_p, __ATOMIC_ACQUIRE, __HIP_MEMORY_SCOPE_AGENT);
    const int na = min(nw, cap);
    const float4* wq4 = (const float4*)WTq;

    for (int it = bid; it < na * NCH; it += NBLK) {
        const int r = it >> 4, c = it & (NCH - 1);
        if (tid < 64) {                  // inline Q projection
            const float4* e4 = (const float4*)(hs_out + (size_t)r * H);
            float s = 0.f;
#pragma unroll 8
            for (int k0 = 0; k0 < 64; ++k0) {
                float4 a = e4[k0];
                float4 w = wq4[k0 * 64 + tid];
                s = fmaf(a.x, w.x, fmaf(a.y, w.y, fmaf(a.z, w.z, fmaf(a.w, w.w, s))));
            }
            qrow[tid] = bq[tid] + s;
        }
        __syncthreads();
        float4 qr[16];
#pragma unroll
        for (int k = 0; k < 16; ++k) qr[k] = ((const float4*)qrow)[k];

        const int k0 = c * CHK + tid;    // 512 threads == CHK: 1 key/thread
        const float4* k4 = (const float4*)(Kp + (size_t)k0 * D);
        float s = 0.f;
#pragma unroll
        for (int k = 0; k < 16; ++k) {
            float4 kv = k4[k];
            s = fmaf(kv.x, qr[k].x, fmaf(kv.y, qr[k].y, fmaf(kv.z, qr[k].z, fmaf(kv.w, qr[k].w, s))));
        }
        s *= PSCALE;
        scores[(size_t)r * LSEQ + k0] = s;

        float m = s;
#pragma unroll
        for (int off = 32; off; off >>= 1) m = fmaxf(m, __shfl_xor(m, off));
        if ((tid & 63) == 0) red[tid >> 6] = m;
        __syncthreads();
        m = red[0];
#pragma unroll
        for (int w = 1; w < 8; ++w) m = fmaxf(m, red[w]);
        __syncthreads();                 // red reuse guard

        float e = __expf(s - m);
#pragma unroll
        for (int off = 32; off; off >>= 1) e += __shfl_xor(e, off);
        if ((tid & 63) == 0) red[tid >> 6] = e;
        __syncthreads();
        if (tid == 0) {
            float v = red[0];
#pragma unroll
            for (int w = 1; w < 8; ++w) v += red[w];
            cmax[it] = m; csum[it] = v;
        }
        __syncthreads();                 // red/qrow guard for next item
    }

    // hs[nw..T) = h*  (8 rows per block iteration, one row per wave)
    {
        float4 hv = ((const float4*)hstar)[tid & 63];
        for (int r = nw + bid * 8 + (tid >> 6); r < T_STEPS; r += NBLK * 8)
            ((float4*)(hs_out + (size_t)r * H))[tid & 63] = hv;
    }
}

// ---------------------------------------------------------------------------
// K2: attnCall — LSE combine + normalize + duplicate-row replicate.
// ONE ROW PER BLOCK, 8192 blocks: maximal resident waves for write MLP
// (r11 lesson: 8 waves/CU -> 1.1 TB/s; wide grids -> ~6.9 TB/s).
// ---------------------------------------------------------------------------
__global__ __launch_bounds__(256) void attnCall_k(
    const int* __restrict__ nw_p, int cap,
    const float* __restrict__ scores, const float* __restrict__ cmax,
    const float* __restrict__ csum, float* __restrict__ out)
{
    const int nw = nw_p[0];
    const int na = min(nw, cap);
    const int r = blockIdx.x;
    const int rs = min(r, nw - 1);
    if (rs >= na) return;                // nw > cap -> fb kernel covers it
    const int tid = threadIdx.x;

    float m = -3.4e38f;
#pragma unroll
    for (int c = 0; c < NCH; ++c) m = fmaxf(m, cmax[rs * NCH + c]);
    float v = 0.f;
#pragma unroll
    for (int c = 0; c < NCH; ++c) v += csum[rs * NCH + c] * __expf(cmax[rs * NCH + c] - m);
    const float inv = 1.0f / v;

    const float4* s4 = (const float4*)(scores + (size_t)rs * LSEQ);
    float4* o4 = (float4*)(out + (size_t)r * LSEQ);
#pragma unroll
    for (int i = 0; i < 8; ++i) {
        float4 sv = s4[tid + 256 * i];
        float4 ov;
        ov.x = __expf(sv.x - m) * inv;
        ov.y = __expf(sv.y - m) * inv;
        ov.z = __expf(sv.z - m) * inv;
        ov.w = __expf(sv.w - m) * inv;
        o4[tid + 256 * i] = ov;
    }
}

// ---------------------------------------------------------------------------
// K3: fallback for source rows >= cap (only when ws can't hold all score
// rows; with the provided ws it never launches). Inline-Q full softmax.
// ---------------------------------------------------------------------------
__global__ __launch_bounds__(256) void attn_fb_k(
    const float* __restrict__ hs, const float* __restrict__ WTq,
    const float* __restrict__ bq, const float* __restrict__ Kp,
    const int* __restrict__ nw_p, int cap, float* __restrict__ out)
{
    const int r = blockIdx.x;
    const int nw = nw_p[0];
    const int rs = min(r, nw - 1);
    if (rs < cap) return;
    const int tid = threadIdx.x;

    __shared__ float srow[LSEQ];
    __shared__ float qrow[D];
    __shared__ float red[4];
    const float4* wq4 = (const float4*)WTq;

    if (tid < 64) {
        const float4* e4 = (const float4*)(hs + (size_t)rs * H);
        float s = 0.f;
#pragma unroll 8
        for (int k0 = 0; k0 < 64; ++k0) {
            float4 a = e4[k0];
            float4 w = wq4[k0 * 64 + tid];
            s = fmaf(a.x, w.x, fmaf(a.y, w.y, fmaf(a.z, w.z, fmaf(a.w, w.w, s))));
        }
        qrow[tid] = bq[tid] + s;
    }
    __syncthreads();
    float4 qr[16];
#pragma unroll
    for (int k = 0; k < 16; ++k) qr[k] = ((const float4*)qrow)[k];

    for (int l = tid; l < LSEQ; l += 256) {
        const float4* k4 = (const float4*)(Kp + (size_t)l * D);
        float s = 0.f;
#pragma unroll
        for (int k = 0; k < 16; ++k) {
            float4 kv = k4[k];
            s = fmaf(kv.x, qr[k].x, fmaf(kv.y, qr[k].y, fmaf(kv.z, qr[k].z, fmaf(kv.w, qr[k].w, s))));
        }
        srow[l] = s * PSCALE;
    }
    __syncthreads();

    float m = -3.4e38f;
    for (int l = tid; l < LSEQ; l += 256) m = fmaxf(m, srow[l]);
#pragma unroll
    for (int off = 32; off; off >>= 1) m = fmaxf(m, __shfl_xor(m, off));
    if ((tid & 63) == 0) red[tid >> 6] = m;
    __syncthreads();
    m = fmaxf(fmaxf(red[0], red[1]), fmaxf(red[2], red[3]));
    __syncthreads();

    float s = 0.f;
    for (int l = tid; l < LSEQ; l += 256) { float e = __expf(srow[l] - m); srow[l] = e; s += e; }
#pragma unroll
    for (int off = 32; off; off >>= 1) s += __shfl_xor(s, off);
    if ((tid & 63) == 0) red[tid >> 6] = s;
    __syncthreads();
    s = red[0] + red[1] + red[2] + red[3];
    float inv = 1.0f / s;

    float4* o4 = (float4*)(out + (size_t)r * LSEQ);
    const float4* s4 = (const float4*)srow;
    for (int i = tid; i < LSEQ / 4; i += 256) {
        float4 v = s4[i];
        v.x *= inv; v.y *= inv; v.z *= inv; v.w *= inv;
        o4[i] = v;
    }
}

extern "C" void kernel_launch(void* const* d_in, const int* in_sizes, int n_in,
                              void* d_out, int out_size, void* d_ws, size_t ws_size,
                              hipStream_t stream)
{
    const float* enc  = (const float*)d_in[1];
    const float* W_ih = (const float*)d_in[2];
    // d_in[3] = W_hh multiplies the always-zero LSTM hidden state -> unused.
    const float* b_ih = (const float*)d_in[4];
    const float* b_hh = (const float*)d_in[5];
    const float* Wq   = (const float*)d_in[6];
    const float* bq   = (const float*)d_in[7];
    const float* Wk   = (const float*)d_in[8];
    const float* bk   = (const float*)d_in[9];

    float* out = (float*)d_out;                       // pointers: 8192*8192
    float* hs  = out + (size_t)T_STEPS * LSEQ;        // hs: 8192*256 (2nd output)

    // ws layout (floats): nw(32) | bar_cnt@32 | bar_gen@48 | hstar@64(256) |
    //   Kp(512K) | WTk(16K) | WTq(16K) | W16v(98304) | cmax(CAP*16) |
    //   csum(CAP*16) | scores(CAP*8192)
    float* wsf     = (float*)d_ws;
    int*   nw_p    = (int*)d_ws;
    int*   bar_cnt = (int*)(wsf + 32);
    int*   bar_gen = (int*)(wsf + 48);
    float* hstar   = wsf + 64;
    float* Kp      = wsf + 64 + 256;
    float* WTk     = Kp + (size_t)LSEQ * D;
    float* WTq     = WTk + 64 * H;
    uint4* W16v    = (uint4*)(WTq + 64 * H);
    size_t off_dyn = 64 + 256 + (size_t)LSEQ * D + 2 * (size_t)64 * H + 24576 * 4;

    size_t wsf_count = ws_size / 4;
    long cap_l = 0;
    if (wsf_count > off_dyn)
        cap_l = (long)((wsf_count - off_dyn) / (LSEQ + 2 * NCH));
    if (cap_l > T_STEPS) cap_l = T_STEPS;
    const int CAP = (int)cap_l;

    float* cmax   = wsf + off_dyn;
    float* csum   = cmax + (size_t)CAP * NCH;
    float* scores = csum + (size_t)CAP * NCH;

    prep_k<<<112, 256, 0, stream>>>(W_ih, Wk, Wq, W16v, WTk, WTq, bar_cnt, bar_gen);
    mid_k<<<NBLK, 512, 0, stream>>>(enc, W16v, b_ih, b_hh, WTk, bk, WTq, bq,
                                    Kp, hs, hstar, nw_p, bar_cnt, bar_gen, CAP,
                                    cmax, csum, scores);
    attnCall_k<<<T_STEPS, 256, 0, stream>>>(nw_p, CAP, scores, cmax, csum, out);
    if (CAP < T_STEPS)
        attn_fb_k<<<T_STEPS, 256, 0, stream>>>(hs, WTq, bq, Kp, nw_p, CAP, out);
}

// Round 13
// 103.932 us; speedup vs baseline: 2.3129x; 1.8030x over previous
//
#include <hip/hip_runtime.h>
#include <stdint.h>

#define T_STEPS 8192
#define LSEQ    8192
#define H       256
#define D       64
#define PSCALE  0.125f   // 1/sqrt(64)
#define CONV_EPS 4e-4f   // convergence tolerance (validated: nw ~ 7)
#define NCH     16       // score chunks per row
#define CHK     512      // keys per chunk (NCH*CHK == LSEQ)

// NOTE (r11/r12 lesson): do NOT fuse these phases into one kernel. The rnn's
// 48xuint4 weight block needs ~192 VGPRs; co-compiled phase code caps the
// allocator (VGPR_Count=112 observed) and spills the weights -> ~5x rnn
// regression. And <=1-block/CU persistent grids cap HBM writes at ~1.1 TB/s.
// This 4-dispatch pipeline (r10) is the measured optimum: 104 us.

typedef _Float16 half2_t __attribute__((ext_vector_type(2)));

#if __has_builtin(__builtin_amdgcn_fdot2)
#define FDOT2(a, b, c) __builtin_amdgcn_fdot2((a), (b), (c), false)
#else
#define FDOT2(a, b, c) fmaf((float)(a).x, (float)(b).x, fmaf((float)(a).y, (float)(b).y, (c)))
#endif

static __device__ __forceinline__ unsigned pack_f16(float a, float b) {
    half2_t h; h.x = (_Float16)a; h.y = (_Float16)b;
    return __builtin_bit_cast(unsigned, h);
}

// ---------------------------------------------------------------------------
// K0: prep — chip-wide weight staging so the single-CU rnn block doesn't pull
// 768 KB of f32 from HBM by itself (~30us at one CU's ~25 GB/s HBM share).
//  (a) W_ih (gates i,g,o) -> f16 SoA: uint4 W16v[p*512 + slot]; rnn reads 48
//      coalesced uint4/thread, 384 KB total, L2/L3-hot from this producer.
//      Same f32->f16 rounding as an in-thread convert -> identical weights.
//  (b) WTk/WTq transposes for the coalesced projection pattern (r8 fix).
// ---------------------------------------------------------------------------
__global__ __launch_bounds__(256) void prep_k(
    const float* __restrict__ W_ih, const float* __restrict__ Wk,
    const float* __restrict__ Wq, uint4* __restrict__ W16v,
    float* __restrict__ WTk, float* __restrict__ WTq)
{
    int flat = blockIdx.x * 256 + threadIdx.x;
    if (flat < 24576) {                 // W16v: 48*512 uint4
        int p = flat >> 9, slot = flat & 511;
        int g = p >> 4, s = p & 15;
        int j = slot >> 1, kc = slot & 1;
        const int goff = (g == 0) ? 0 : (g == 1 ? 512 : 768);
        const float* src = W_ih + (size_t)(goff + j) * H + kc * 128 + s * 8;
        uint4 u;
        u.x = pack_f16(src[0], src[1]);
        u.y = pack_f16(src[2], src[3]);
        u.z = pack_f16(src[4], src[5]);
        u.w = pack_f16(src[6], src[7]);
        W16v[flat] = u;
    } else if (flat < 24576 + 4096) {   // WT transposes: 4096 float4 each
        int f = flat - 24576;
        int d = f & 63, k0 = f >> 6;
        ((float4*)WTk)[f] = *(const float4*)(Wk + d * H + k0 * 4);
        ((float4*)WTq)[f] = *(const float4*)(Wq + d * H + k0 * 4);
    }
}

// ---------------------------------------------------------------------------
// K1: block 0 = LSTM recurrence (f16-SoA weight load, register-resident);
//     blocks 1..256 = Kp projection riding the same dispatch.
// ---------------------------------------------------------------------------
__global__ __launch_bounds__(512, 2) void rnn_kp_k(
    const float* __restrict__ enc, const uint4* __restrict__ W16v,
    const float* __restrict__ b_ih, const float* __restrict__ b_hh,
    const float* __restrict__ WTk, const float* __restrict__ bk,
    float* __restrict__ Kp,
    float* __restrict__ hs_out, float* __restrict__ hstar, int* __restrict__ nw_out)
{
    const int tid = threadIdx.x;
    if (blockIdx.x != 0) {
        // ---- Kp: 4 rows per wave, coalesced WTk reads ----
        const int lane = tid & 63;
        const int wid  = ((int)blockIdx.x - 1) * 8 + (tid >> 6);  // 0..2047
        const float bkl = bk[lane];
        const float4* wk4 = (const float4*)WTk;
        const int r0 = wid * 4;
        const float4* e0 = (const float4*)(enc + (size_t)(r0 + 0) * H);
        const float4* e1 = (const float4*)(enc + (size_t)(r0 + 1) * H);
        const float4* e2 = (const float4*)(enc + (size_t)(r0 + 2) * H);
        const float4* e3 = (const float4*)(enc + (size_t)(r0 + 3) * H);
        float s0 = 0.f, s1 = 0.f, s2 = 0.f, s3 = 0.f;
#pragma unroll 8
        for (int k0 = 0; k0 < 64; ++k0) {
            float4 w = wk4[k0 * 64 + lane];
            float4 a0 = e0[k0], a1 = e1[k0], a2 = e2[k0], a3 = e3[k0];
            s0 = fmaf(a0.x, w.x, fmaf(a0.y, w.y, fmaf(a0.z, w.z, fmaf(a0.w, w.w, s0))));
            s1 = fmaf(a1.x, w.x, fmaf(a1.y, w.y, fmaf(a1.z, w.z, fmaf(a1.w, w.w, s1))));
            s2 = fmaf(a2.x, w.x, fmaf(a2.y, w.y, fmaf(a2.z, w.z, fmaf(a2.w, w.w, s2))));
            s3 = fmaf(a3.x, w.x, fmaf(a3.y, w.y, fmaf(a3.z, w.z, fmaf(a3.w, w.w, s3))));
        }
        Kp[(size_t)(r0 + 0) * D + lane] = bkl + s0;
        Kp[(size_t)(r0 + 1) * D + lane] = bkl + s1;
        Kp[(size_t)(r0 + 2) * D + lane] = bkl + s2;
        Kp[(size_t)(r0 + 3) * D + lane] = bkl + s3;
        return;
    }

    // ---- block 0: the recurrence ----
    const int j  = tid >> 1;          // hidden element [0,256)
    const int kc = tid & 1;           // K-chunk: cols [128*kc, 128*kc+128)

    uint4 wv[48];                     // 48 coalesced uint4 = this thread's
#pragma unroll                        // 3x128 f16 weights (SoA from prep_k)
    for (int p = 0; p < 48; ++p) wv[p] = W16v[p * 512 + tid];

    const float bi = b_ih[j] + b_hh[j];
    const float bg = b_ih[512 + j] + b_hh[512 + j];
    const float bo = b_ih[768 + j] + b_hh[768 + j];

    __shared__ half2_t hp[H / 2];     // h_{t-1} packed f16x2, broadcast-read

    float hcur = enc[(size_t)(LSEQ - 1) * H + j];   // h0 = enc[-1]
    {
        float hnext = __shfl_xor(hcur, 2);          // pack partner h_{j^1}
        if ((tid & 3) == 0) { half2_t p; p.x = (_Float16)hcur; p.y = (_Float16)hnext; hp[tid >> 2] = p; }
    }
    __syncthreads();

    int nw = T_STEPS;
    int streak = 0;
    for (int t = 1; t <= T_STEPS; ++t) {
        float ai = 0.f, ag = 0.f, ao = 0.f;
        const uint4* hp4 = (const uint4*)hp;        // 16 uint4 per K-chunk
#pragma unroll
        for (int q = 0; q < 16; ++q) {
            uint4 u = hp4[kc * 16 + q];
            half2_t h0 = __builtin_bit_cast(half2_t, u.x);
            half2_t h1 = __builtin_bit_cast(half2_t, u.y);
            half2_t h2 = __builtin_bit_cast(half2_t, u.z);
            half2_t h3 = __builtin_bit_cast(half2_t, u.w);
            uint4 wiu = wv[q], wgu = wv[16 + q], wou = wv[32 + q];
            ai = FDOT2(__builtin_bit_cast(half2_t, wiu.x), h0, ai);
            ag = FDOT2(__builtin_bit_cast(half2_t, wgu.x), h0, ag);
            ao = FDOT2(__builtin_bit_cast(half2_t, wou.x), h0, ao);
            ai = FDOT2(__builtin_bit_cast(half2_t, wiu.y), h1, ai);
            ag = FDOT2(__builtin_bit_cast(half2_t, wgu.y), h1, ag);
            ao = FDOT2(__builtin_bit_cast(half2_t, wou.y), h1, ao);
            ai = FDOT2(__builtin_bit_cast(half2_t, wiu.z), h2, ai);
            ag = FDOT2(__builtin_bit_cast(half2_t, wgu.z), h2, ag);
            ao = FDOT2(__builtin_bit_cast(half2_t, wou.z), h2, ao);
            ai = FDOT2(__builtin_bit_cast(half2_t, wiu.w), h3, ai);
            ag = FDOT2(__builtin_bit_cast(half2_t, wgu.w), h3, ag);
            ao = FDOT2(__builtin_bit_cast(half2_t, wou.w), h3, ao);
        }
        ai += __shfl_xor(ai, 1); ag += __shfl_xor(ag, 1); ao += __shfl_xor(ao, 1);
        ai += bi; ag += bg; ao += bo;

        float si = 1.0f / (1.0f + __expf(-ai));
        float eg = __expf(-2.0f * ag); float tg = (1.0f - eg) / (1.0f + eg);
        float so = 1.0f / (1.0f + __expf(-ao));
        float c  = si * tg;
        float ec = __expf(-2.0f * c);  float tc = (1.0f - ec) / (1.0f + ec);
        float hn = so * tc;

        int moving = (kc == 0 && fabsf(hn - hcur) >= CONV_EPS) ? 1 : 0;
        int nmov = __syncthreads_count(moving);     // guards hp reads

        hcur = hn;
        float hnext = __shfl_xor(hn, 2);
        if ((tid & 3) == 0) { half2_t p; p.x = (_Float16)hn; p.y = (_Float16)hnext; hp[tid >> 2] = p; }
        if (kc == 0) hs_out[(size_t)(t - 1) * H + j] = hn;
        __syncthreads();                            // publish new hp

        streak = (nmov == 0) ? streak + 1 : 0;
        if (streak >= 2) { nw = t; break; }
    }
    if (kc == 0) hstar[j] = hcur;
    if (tid == 0) nw_out[0] = nw;
}

// ---------------------------------------------------------------------------
// K2: attnA + hs-fill. Item (r,c): compute Q[r] inline (same fmaf order as
// a separate Qp projection -> identical bits), 512 scores -> ws, chunk max
// and chunk exp-sum. Then all blocks grid-stride the hs[nw..T) fill.
// ---------------------------------------------------------------------------
__global__ __launch_bounds__(256) void attnA_fill_k(
    const float* __restrict__ hs, const float* __restrict__ WTq,
    const float* __restrict__ bq, const float* __restrict__ Kp,
    const float* __restrict__ hstar, float* __restrict__ hs_out,
    const int* __restrict__ nw_p, int cap,
    float* __restrict__ scores, float* __restrict__ cmax, float* __restrict__ csum)
{
    const int nw = nw_p[0];
    const int na = min(nw, cap);
    const int tid = threadIdx.x;
    __shared__ float qrow[D];
    __shared__ float red[4];
    const float4* wq4 = (const float4*)WTq;

    for (int it = blockIdx.x; it < na * NCH; it += gridDim.x) {
        const int r = it >> 4, c = it & (NCH - 1);
        if (tid < 64) {                  // inline Q projection (bitwise == Qp)
            const float4* e4 = (const float4*)(hs + (size_t)r * H);
            float s = 0.f;
#pragma unroll 8
            for (int k0 = 0; k0 < 64; ++k0) {
                float4 a = e4[k0];
                float4 w = wq4[k0 * 64 + tid];
                s = fmaf(a.x, w.x, fmaf(a.y, w.y, fmaf(a.z, w.z, fmaf(a.w, w.w, s))));
            }
            qrow[tid] = bq[tid] + s;
        }
        __syncthreads();
        float4 qr[16];
#pragma unroll
        for (int k = 0; k < 16; ++k) qr[k] = ((const float4*)qrow)[k];

        const int k0 = c * CHK + tid;         // and k0+256
        float s01[2];
#pragma unroll
        for (int h = 0; h < 2; ++h) {
            const float4* k4 = (const float4*)(Kp + (size_t)(k0 + 256 * h) * D);
            float s = 0.f;
#pragma unroll
            for (int k = 0; k < 16; ++k) {
                float4 kv = k4[k];
                s = fmaf(kv.x, qr[k].x, fmaf(kv.y, qr[k].y, fmaf(kv.z, qr[k].z, fmaf(kv.w, qr[k].w, s))));
            }
            s01[h] = s * PSCALE;
            scores[(size_t)r * LSEQ + k0 + 256 * h] = s01[h];
        }

        float m = fmaxf(s01[0], s01[1]);
#pragma unroll
        for (int off = 32; off; off >>= 1) m = fmaxf(m, __shfl_xor(m, off));
        if ((tid & 63) == 0) red[tid >> 6] = m;
        __syncthreads();
        m = fmaxf(fmaxf(red[0], red[1]), fmaxf(red[2], red[3]));
        __syncthreads();                       // red reuse guard

        float e = __expf(s01[0] - m) + __expf(s01[1] - m);
#pragma unroll
        for (int off = 32; off; off >>= 1) e += __shfl_xor(e, off);
        if ((tid & 63) == 0) red[tid >> 6] = e;
        __syncthreads();
        if (tid == 0) { cmax[it] = m; csum[it] = red[0] + red[1] + red[2] + red[3]; }
        __syncthreads();                       // red/qrow guard for next item
    }

    // hs[nw..T) = h*  (output-only region; 4 rows per block iteration)
    float4 hv = ((const float4*)hstar)[tid & 63];
    for (int r = nw + blockIdx.x * 4 + (tid >> 6); r < T_STEPS; r += gridDim.x * 4)
        ((float4*)(hs_out + (size_t)r * H))[tid & 63] = hv;
}

// ---------------------------------------------------------------------------
// K3: attnCall — merged LSE-combine + normalize + duplicate-row replicate.
// Grid-strides ALL 8192 output rows; source row rs = min(r, nw-1). Pure
// write BW (~268 MB), the structural floor of this problem.
// ---------------------------------------------------------------------------
__global__ __launch_bounds__(256) void attnCall_k(
    const int* __restrict__ nw_p, int cap,
    const float* __restrict__ scores, const float* __restrict__ cmax,
    const float* __restrict__ csum, float* __restrict__ out)
{
    const int nw = nw_p[0];
    const int na = min(nw, cap);
    const int tid = threadIdx.x;

    for (int r = blockIdx.x; r < T_STEPS; r += gridDim.x) {
        const int rs = min(r, nw - 1);
        if (rs >= na) continue;                // only when nw > cap -> fb path
        float m = -3.4e38f;
#pragma unroll
        for (int c = 0; c < NCH; ++c) m = fmaxf(m, cmax[rs * NCH + c]);
        float v = 0.f;
#pragma unroll
        for (int c = 0; c < NCH; ++c) v += csum[rs * NCH + c] * __expf(cmax[rs * NCH + c] - m);
        const float inv = 1.0f / v;

        const float4* s4 = (const float4*)(scores + (size_t)rs * LSEQ);
        float4* o4 = (float4*)(out + (size_t)r * LSEQ);
        for (int i = tid; i < LSEQ / 4; i += 256) {
            float4 sv = s4[i];
            float4 ov;
            ov.x = __expf(sv.x - m) * inv;
            ov.y = __expf(sv.y - m) * inv;
            ov.z = __expf(sv.z - m) * inv;
            ov.w = __expf(sv.w - m) * inv;
            o4[i] = ov;
        }
    }
}

// ---------------------------------------------------------------------------
// K4: fallback for source rows >= cap (launched only when CAP < T_STEPS;
// with the provided ws it never is). Inline-Q full softmax of row rs -> r.
// ---------------------------------------------------------------------------
__global__ __launch_bounds__(256) void attn_fb_k(
    const float* __restrict__ hs, const float* __restrict__ WTq,
    const float* __restrict__ bq, const float* __restrict__ Kp,
    const int* __restrict__ nw_p, int cap, float* __restrict__ out)
{
    const int r = blockIdx.x;
    const int nw = nw_p[0];
    const int rs = min(r, nw - 1);
    if (rs < cap) return;
    const int tid = threadIdx.x;

    __shared__ float srow[LSEQ];
    __shared__ float qrow[D];
    __shared__ float red[4];
    const float4* wq4 = (const float4*)WTq;

    if (tid < 64) {
        const float4* e4 = (const float4*)(hs + (size_t)rs * H);
        float s = 0.f;
#pragma unroll 8
        for (int k0 = 0; k0 < 64; ++k0) {
            float4 a = e4[k0];
            float4 w = wq4[k0 * 64 + tid];
            s = fmaf(a.x, w.x, fmaf(a.y, w.y, fmaf(a.z, w.z, fmaf(a.w, w.w, s))));
        }
        qrow[tid] = bq[tid] + s;
    }
    __syncthreads();
    float4 qr[16];
#pragma unroll
    for (int k = 0; k < 16; ++k) qr[k] = ((const float4*)qrow)[k];

    for (int l = tid; l < LSEQ; l += 256) {
        const float4* k4 = (const float4*)(Kp + (size_t)l * D);
        float s = 0.f;
#pragma unroll
        for (int k = 0; k < 16; ++k) {
            float4 kv = k4[k];
            s = fmaf(kv.x, qr[k].x, fmaf(kv.y, qr[k].y, fmaf(kv.z, qr[k].z, fmaf(kv.w, qr[k].w, s))));
        }
        srow[l] = s * PSCALE;
    }
    __syncthreads();

    float m = -3.4e38f;
    for (int l = tid; l < LSEQ; l += 256) m = fmaxf(m, srow[l]);
#pragma unroll
    for (int off = 32; off; off >>= 1) m = fmaxf(m, __shfl_xor(m, off));
    if ((tid & 63) == 0) red[tid >> 6] = m;
    __syncthreads();
    m = fmaxf(fmaxf(red[0], red[1]), fmaxf(red[2], red[3]));
    __syncthreads();

    float s = 0.f;
    for (int l = tid; l < LSEQ; l += 256) { float e = __expf(srow[l] - m); srow[l] = e; s += e; }
#pragma unroll
    for (int off = 32; off; off >>= 1) s += __shfl_xor(s, off);
    if ((tid & 63) == 0) red[tid >> 6] = s;
    __syncthreads();
    s = red[0] + red[1] + red[2] + red[3];
    float inv = 1.0f / s;

    float4* o4 = (float4*)(out + (size_t)r * LSEQ);
    const float4* s4 = (const float4*)srow;
    for (int i = tid; i < LSEQ / 4; i += 256) {
        float4 v = s4[i];
        v.x *= inv; v.y *= inv; v.z *= inv; v.w *= inv;
        o4[i] = v;
    }
}

extern "C" void kernel_launch(void* const* d_in, const int* in_sizes, int n_in,
                              void* d_out, int out_size, void* d_ws, size_t ws_size,
                              hipStream_t stream)
{
    const float* enc  = (const float*)d_in[1];
    const float* W_ih = (const float*)d_in[2];
    // d_in[3] = W_hh multiplies the always-zero LSTM hidden state -> unused.
    const float* b_ih = (const float*)d_in[4];
    const float* b_hh = (const float*)d_in[5];
    const float* Wq   = (const float*)d_in[6];
    const float* bq   = (const float*)d_in[7];
    const float* Wk   = (const float*)d_in[8];
    const float* bk   = (const float*)d_in[9];

    float* out = (float*)d_out;                       // pointers: 8192*8192
    float* hs  = out + (size_t)T_STEPS * LSEQ;        // hs: 8192*256 (2nd output)

    // ws layout (floats): nw(16) | hstar(256) | Kp(512K) | WTk(16K) |
    //   WTq(16K) | W16v(98304 = 384KB) | cmax(CAP*16) | csum(CAP*16) |
    //   scores(CAP*8192)
    float* wsf   = (float*)d_ws;
    int*   nw_p  = (int*)d_ws;
    float* hstar = wsf + 16;
    float* Kp    = wsf + 16 + 256;
    float* WTk   = Kp + (size_t)LSEQ * D;
    float* WTq   = WTk + 64 * H;
    uint4* W16v  = (uint4*)(WTq + 64 * H);
    size_t off_dyn = 16 + 256 + (size_t)LSEQ * D + 2 * (size_t)64 * H + 24576 * 4;

    size_t wsf_count = ws_size / 4;
    long cap_l = 0;
    if (wsf_count > off_dyn)
        cap_l = (long)((wsf_count - off_dyn) / (LSEQ + 2 * NCH));
    if (cap_l > T_STEPS) cap_l = T_STEPS;
    const int CAP = (int)cap_l;

    float* cmax   = wsf + off_dyn;
    float* csum   = cmax + (size_t)CAP * NCH;
    float* scores = csum + (size_t)CAP * NCH;

    prep_k<<<112, 256, 0, stream>>>(W_ih, Wk, Wq, W16v, WTk, WTq);
    rnn_kp_k<<<257, 512, 0, stream>>>(enc, W16v, b_ih, b_hh, WTk, bk, Kp, hs, hstar, nw_p);
    attnA_fill_k<<<1024, 256, 0, stream>>>(hs, WTq, bq, Kp, hstar, hs, nw_p, CAP, scores, cmax, csum);
    attnCall_k<<<2048, 256, 0, stream>>>(nw_p, CAP, scores, cmax, csum, out);
    if (CAP < T_STEPS)
        attn_fb_k<<<T_STEPS, 256, 0, stream>>>(hs, WTq, bq, Kp, nw_p, CAP, out);
}